// Round 1
// baseline (267.630 us; speedup 1.0000x reference)
//
#include <hip/hip_runtime.h>
#include <math.h>

// SpanPairVAHead on MI355X (gfx950).
// Dtype map (established rounds 0-3): ALL float tensors f32, spans int
// (32/64 sniffed on device), OUTPUT f32. Internal activations bf16 for MFMA.
//
// R8: fuse the tail. reduce_bias_gelu + gemm2_head (64 blocks = 0.25/CU,
// pure latency) -> one 256-block kernel (1/CU): stage W2 f32->bf16T in LDS
// (kills W2T transpose), stage x1 = gelu(P0+P1+b1) tile in LDS, barrier-free
// 8-step MFMA K-loop, gelu+head epilogue with 4-way shfl-split dot.
// 4 launches. x1 and W2T buffers eliminated.
//
// B=64, L=512, H=1024, Q=64, VA_H=256. Pairs = B*Q = 4096.

typedef __attribute__((ext_vector_type(4))) float f32x4;
typedef __attribute__((ext_vector_type(8))) short bf16x8;

#define NPAIR 4096
#define LSEQ 512
#define HDIM 1024

#if defined(__has_builtin)
#if __has_builtin(__builtin_amdgcn_global_load_lds)
#define HAVE_GLDS 1
#endif
#endif
#ifndef HAVE_GLDS
#define HAVE_GLDS 0
#endif

// Pack two f32 -> bf16 pair, round-to-nearest (half-up; differs from RNE only
// on exact ties, p~2^-16). v_perm_b32 grabs the two high halves.
__device__ __forceinline__ unsigned int pack2(float lo, float hi) {
  const unsigned int a = __float_as_uint(lo) + 0x8000u;
  const unsigned int b = __float_as_uint(hi) + 0x8000u;
  return __builtin_amdgcn_perm(b, a, 0x07060302u);
}
__device__ __forceinline__ unsigned short f2bf(float f) {
  return (unsigned short)((__float_as_uint(f) + 0x8000u) >> 16);
}
__device__ __forceinline__ float gelu(float x) {
  return 0.5f * x * (1.f + erff(x * 0.70710678118654752f));
}

// ---------------------------------------------------------------------------
// Fused span pooling via MFMA (unchanged from R7). One block per (batch,
// 64-col H-slice): 1024 blocks = 4/CU. Rows 0..63 = asp masks, 64..127 = opi.
// A-frags from span compares in registers; B staged f32->bf16 transposed
// ([n][k]) double-buffered, 1 barrier/iter. Epilogue S[128][68] unions Bl.
// ---------------------------------------------------------------------------
__global__ __launch_bounds__(256, 4) void pool_mfma_kernel(
    const float* __restrict__ hs, const int* __restrict__ spans,
    const int* __restrict__ qmask, unsigned short* __restrict__ hpair) {
  __shared__ __align__(16) unsigned char smem[34816];  // max(2*64*40*2, 128*68*4)
  __shared__ float scl[128];
  typedef unsigned short BlT[64][40];
  BlT* Bl = (BlT*)smem;                  // Bl[2][64][40]
  float(*S)[68] = (float(*)[68])smem;    // S[128][68] (epilogue only)

  const int b = blockIdx.x >> 4;
  const int n0 = (blockIdx.x & 15) * 64;
  const int tid = threadIdx.x;
  const int lane = tid & 63;
  const int lm = lane & 15, quad = lane >> 4;
  const int wm = (tid >> 6) * 32;  // wave's mask-row base

  const bool is64 =
      (spans[1] == 0) && (spans[3] == 0) && (spans[5] == 0) && (spans[7] == 0);

  auto span_of = [&](int r, int& s, int& e) {
    const int q = r & 63, t = r >> 6;
    const int idx = (b * 64 + q) * 4 + t * 2;
    s = is64 ? spans[idx * 2] : spans[idx];
    e = is64 ? spans[idx * 2 + 2] : spans[idx + 1];
    if (s < 2) { s = 1; e = 1; }  // invalid -> [SEP]
  };
  int s0, e0, s1, e1;
  span_of(wm + lm, s0, e0);
  span_of(wm + 16 + lm, s1, e1);

  if (tid < 128) {
    int s, e;
    span_of(tid, s, e);
    const int c = (e >= s) ? (e - s + 1) : 0;
    const float sc = 1.f / (float)(c < 1 ? 1 : c);
    scl[tid] = (qmask[b * 64 + (tid & 63)] != 0) ? sc : 0.f;
  }

  f32x4 acc[2][4];
#pragma unroll
  for (int f = 0; f < 2; ++f)
#pragma unroll
    for (int g = 0; g < 4; ++g) acc[f][g] = f32x4{0.f, 0.f, 0.f, 0.f};

  const float* hsb = hs + (size_t)b * (LSEQ * HDIM);
  const int nl = tid & 63;        // staged column (wave-coalesced)
  const int kw = (tid >> 6) * 8;  // wave's k-offset within 32-chunk

  auto load8 = [&](int kbase, unsigned int (&tmp)[4]) {
    const float* src = hsb + (size_t)(kbase + kw) * HDIM + n0 + nl;
#pragma unroll
    for (int i = 0; i < 4; ++i) {
      const float f0 = src[(size_t)(2 * i) * HDIM];
      const float f1 = src[(size_t)(2 * i + 1) * HDIM];
      tmp[i] = pack2(f0, f1);
    }
  };

  unsigned int tmp[4];
  load8(0, tmp);
  *(uint4*)&Bl[0][nl][kw] = make_uint4(tmp[0], tmp[1], tmp[2], tmp[3]);

  for (int it = 0; it < 16; ++it) {
    const int k0 = it * 32;
    __syncthreads();  // buf[it&1] staged; prior reads of buf[(it+1)&1] done
    if (it < 15) load8(k0 + 32, tmp);

    bf16x8 a0, a1;
#pragma unroll
    for (int j = 0; j < 8; ++j) {
      const int k = k0 + quad * 8 + j;
      a0[j] = (short)((k >= s0 && k <= e0) ? 0x3F80 : 0);
      a1[j] = (short)((k >= s1 && k <= e1) ? 0x3F80 : 0);
    }
    const BlT& Bc = Bl[it & 1];
#pragma unroll
    for (int g = 0; g < 4; ++g) {
      bf16x8 bg = *(const bf16x8*)&Bc[g * 16 + lm][quad * 8];
      acc[0][g] = __builtin_amdgcn_mfma_f32_16x16x32_bf16(a0, bg, acc[0][g], 0, 0, 0);
      acc[1][g] = __builtin_amdgcn_mfma_f32_16x16x32_bf16(a1, bg, acc[1][g], 0, 0, 0);
    }
    if (it < 15) {
      *(uint4*)&Bl[(it + 1) & 1][nl][kw] = make_uint4(tmp[0], tmp[1], tmp[2], tmp[3]);
    }
  }

  __syncthreads();  // all MFMA LDS reads done before S overwrites Bl
  // C/D layout (m89): col = lane&15, row = quad*4 + reg.
#pragma unroll
  for (int f = 0; f < 2; ++f)
#pragma unroll
    for (int g = 0; g < 4; ++g)
#pragma unroll
      for (int r = 0; r < 4; ++r)
        S[wm + f * 16 + quad * 4 + r][g * 16 + lm] = acc[f][g][r];
  __syncthreads();

  // Store h_pair: thread q = tid>>2, 16-col group cg = (tid&3)*16.
  const int q = tid >> 2;
  const int cg = (tid & 3) * 16;
  const float sA = scl[q], sO = scl[64 + q];
  unsigned short* dst = hpair + (size_t)(b * 64 + q) * 3072 + n0 + cg;
#pragma unroll
  for (int h = 0; h < 2; ++h) {
    float a[8], o[8];
#pragma unroll
    for (int i = 0; i < 8; ++i) {
      a[i] = S[q][cg + h * 8 + i] * sA;
      o[i] = S[64 + q][cg + h * 8 + i] * sO;
    }
    uint4 wa, wo, wp;
    wa.x = pack2(a[0], a[1]); wa.y = pack2(a[2], a[3]);
    wa.z = pack2(a[4], a[5]); wa.w = pack2(a[6], a[7]);
    wo.x = pack2(o[0], o[1]); wo.y = pack2(o[2], o[3]);
    wo.z = pack2(o[4], o[5]); wo.w = pack2(o[6], o[7]);
    wp.x = pack2(a[0] * o[0], a[1] * o[1]); wp.y = pack2(a[2] * o[2], a[3] * o[3]);
    wp.z = pack2(a[4] * o[4], a[5] * o[5]); wp.w = pack2(a[6] * o[6], a[7] * o[7]);
    *(uint4*)(dst + h * 8) = wa;
    *(uint4*)(dst + 1024 + h * 8) = wo;
    *(uint4*)(dst + 2048 + h * 8) = wp;
  }
}

// ---------------------------------------------------------------------------
// W1 transpose only (W2 is now consumed in-place by the fused tail kernel).
// 768 blocks: W1 (3072x256) f32 -> W1T (256x3072) bf16.
// ---------------------------------------------------------------------------
__global__ void transpose_w1(const float* __restrict__ W1,
                             unsigned short* __restrict__ W1T) {
  __shared__ float t[32][33];
  const int R = 3072, C = 256;
  const int c0 = (blockIdx.x & 7) * 32, r0 = (blockIdx.x >> 3) * 32;
  const int x = threadIdx.x, y = threadIdx.y;  // (32, 8)
#pragma unroll
  for (int i = 0; i < 32; i += 8)
    t[y + i][x] = W1[(size_t)(r0 + y + i) * C + c0 + x];
  __syncthreads();
#pragma unroll
  for (int i = 0; i < 32; i += 8)
    W1T[(size_t)(c0 + y + i) * R + r0 + x] = f2bf(t[x][y + i]);
}

// ---------------------------------------------------------------------------
// Split-K GEMM1 partial (unchanged from R7): P[z] = A(MxKh slice) @ Bt^T,
// raw f32 sums. 64x64 tile, BK=32, 4 waves, 2x2 mfma, global_load_lds w=16.
// ---------------------------------------------------------------------------
__global__ __launch_bounds__(256) void gemm_bt_partial(
    const unsigned short* __restrict__ A, const unsigned short* __restrict__ Bt,
    float* __restrict__ P, int M, int N, int K, int KH) {
  __shared__ __align__(16) unsigned short Al[64][32];
  __shared__ __align__(16) unsigned short Bl[64][32];
  const int bm = blockIdx.x * 64, bn = blockIdx.y * 64;
  const int kz = blockIdx.z * KH;
  const int tid = threadIdx.x;
  const int wave = tid >> 6, lane = tid & 63;
  const int wm = (wave & 1) * 32, wn = (wave >> 1) * 32;
  const int lm = lane & 15, lk = (lane >> 4) * 8;

  const int srow = wave * 16 + (lane >> 2);
  const int scol = (lane & 3) * 8;
  const unsigned short* ga = A + (size_t)(bm + srow) * K + kz + scol;
  const unsigned short* gb = Bt + (size_t)(bn + srow) * K + kz + scol;
  unsigned short* la = &Al[0][0] + wave * 512;  // wave-uniform LDS chunk base
  unsigned short* lb = &Bl[0][0] + wave * 512;

  f32x4 acc00 = {0.f, 0.f, 0.f, 0.f}, acc01 = {0.f, 0.f, 0.f, 0.f};
  f32x4 acc10 = {0.f, 0.f, 0.f, 0.f}, acc11 = {0.f, 0.f, 0.f, 0.f};

  for (int k0 = 0; k0 < KH; k0 += 32) {
#if HAVE_GLDS
    __builtin_amdgcn_global_load_lds(ga + k0, la, 16, 0, 0);
    __builtin_amdgcn_global_load_lds(gb + k0, lb, 16, 0, 0);
#else
    *(uint4*)(la + lane * 8) = *(const uint4*)(ga + k0);
    *(uint4*)(lb + lane * 8) = *(const uint4*)(gb + k0);
#endif
    __syncthreads();  // drains vmcnt (incl. lds-DMA) before frag reads
    bf16x8 a0 = *(const bf16x8*)&Al[wm + lm][lk];
    bf16x8 a1 = *(const bf16x8*)&Al[wm + 16 + lm][lk];
    bf16x8 b0 = *(const bf16x8*)&Bl[wn + lm][lk];
    bf16x8 b1 = *(const bf16x8*)&Bl[wn + 16 + lm][lk];
    acc00 = __builtin_amdgcn_mfma_f32_16x16x32_bf16(a0, b0, acc00, 0, 0, 0);
    acc01 = __builtin_amdgcn_mfma_f32_16x16x32_bf16(a0, b1, acc01, 0, 0, 0);
    acc10 = __builtin_amdgcn_mfma_f32_16x16x32_bf16(a1, b0, acc10, 0, 0, 0);
    acc11 = __builtin_amdgcn_mfma_f32_16x16x32_bf16(a1, b1, acc11, 0, 0, 0);
    __syncthreads();
  }

  float* Pz = P + (size_t)blockIdx.z * M * N;
  const int r0 = bm + wm + ((lane >> 4) << 2);
  const int c0 = bn + wn + lm;
  auto emit = [&](f32x4 v, int row0, int col) {
#pragma unroll
    for (int r = 0; r < 4; ++r) Pz[(size_t)(row0 + r) * N + col] = v[r];
  };
  emit(acc00, r0, c0);
  emit(acc10, r0 + 16, c0);
  emit(acc01, r0, c0 + 16);
  emit(acc11, r0 + 16, c0 + 16);
}

// ---------------------------------------------------------------------------
// Fused tail: split-K reduce + b1 + gelu -> x1 tile (LDS), GEMM2 (16x128,
// K=256) vs W2 staged f32->bf16T in LDS, gelu+b2 -> S2, head dot W3,
// sigmoid*8+1, *qmask. 256 blocks x 16 pairs = 1 block/CU. Single barrier
// before a fully in-LDS K-loop (no per-iter syncs). Rows padded to 264
// bf16 (33 x 16B slots, odd) -> even bank-group spread on ds_read_b128.
// ---------------------------------------------------------------------------
__global__ __launch_bounds__(256) void tail_kernel(
    const float* __restrict__ P, const float* __restrict__ b1,
    const float* __restrict__ W2, const float* __restrict__ b2,
    const float* __restrict__ W3, const float* __restrict__ b3,
    const int* __restrict__ qmask, float* __restrict__ out) {
  __shared__ __align__(16) unsigned short Bl[128 * 264];  // W2^T [n][k] bf16
  __shared__ __align__(16) unsigned short Al[16 * 264];   // x1 tile [m][k] bf16
  __shared__ float S2[16][132];                           // x2 tile f32
  __shared__ float w3[256];

  const int m0 = blockIdx.x * 16;
  const int tid = threadIdx.x;
  const int wave = tid >> 6, lane = tid & 63;
  const int lm = lane & 15, quad = lane >> 4;
  const int wn = wave * 32;  // wave's 32-col slice of N=128

  w3[tid] = W3[tid];  // 128x2 f32

  // --- Stage W2 (256x128 f32) -> Bl[n][k] bf16. Coalesced row reads, packed
  // u32 LDS writes (one-time; 64 iters/thread).
  for (int e = tid; e < 128 * 128; e += 256) {
    const int k2 = e >> 7;      // k-pair 0..127
    const int n = e & 127;      // col 0..127
    const float lo = W2[(size_t)(2 * k2) * 128 + n];
    const float hi = W2[(size_t)(2 * k2 + 1) * 128 + n];
    *(unsigned int*)((char*)Bl + (size_t)n * 528 + k2 * 4) = pack2(lo, hi);
  }

  // --- Stage x1 tile: x1[r][k] = gelu(P0 + P1 + b1). 16 elems/thread.
  {
    const int row = tid >> 4;   // 0..15
    const int slot = tid & 15;  // 8-elem slot
#pragma unroll
    for (int ss = 0; ss < 2; ++ss) {
      const int s = slot + ss * 16;  // 0..31
      const float* p0 = P + (size_t)(m0 + row) * 256 + s * 8;
      const float* p1 = p0 + (size_t)NPAIR * 256;
      float4 a0 = *(const float4*)p0, a1 = *(const float4*)(p0 + 4);
      float4 c0 = *(const float4*)p1, c1 = *(const float4*)(p1 + 4);
      float4 ba = *(const float4*)(b1 + s * 8);
      float4 bb = *(const float4*)(b1 + s * 8 + 4);
      const float v0 = gelu(a0.x + c0.x + ba.x);
      const float v1 = gelu(a0.y + c0.y + ba.y);
      const float v2 = gelu(a0.z + c0.z + ba.z);
      const float v3 = gelu(a0.w + c0.w + ba.w);
      const float v4 = gelu(a1.x + c1.x + bb.x);
      const float v5 = gelu(a1.y + c1.y + bb.y);
      const float v6 = gelu(a1.z + c1.z + bb.z);
      const float v7 = gelu(a1.w + c1.w + bb.w);
      uint4 w;
      w.x = pack2(v0, v1); w.y = pack2(v2, v3);
      w.z = pack2(v4, v5); w.w = pack2(v6, v7);
      *(uint4*)((char*)Al + (size_t)row * 528 + s * 16) = w;
    }
  }
  __syncthreads();  // LDS read-only from here: barrier-free K-loop

  // --- GEMM2: M=16 (1 frag), N=128 (2 frags/wave), K=256 (8 steps).
  f32x4 acc[2];
  acc[0] = f32x4{0.f, 0.f, 0.f, 0.f};
  acc[1] = f32x4{0.f, 0.f, 0.f, 0.f};
#pragma unroll
  for (int ks = 0; ks < 8; ++ks) {
    bf16x8 a = *(const bf16x8*)((char*)Al + (size_t)lm * 528 + ks * 64 + quad * 16);
#pragma unroll
    for (int g = 0; g < 2; ++g) {
      const int n = wn + g * 16 + lm;
      bf16x8 b = *(const bf16x8*)((char*)Bl + (size_t)n * 528 + ks * 64 + quad * 16);
      acc[g] = __builtin_amdgcn_mfma_f32_16x16x32_bf16(a, b, acc[g], 0, 0, 0);
    }
  }

  // --- x2 = gelu(acc + b2). C/D: col = lane&15, row = quad*4 + reg.
#pragma unroll
  for (int g = 0; g < 2; ++g) {
    const int col = wn + g * 16 + lm;
    const float bc = b2[col];
#pragma unroll
    for (int r = 0; r < 4; ++r) S2[quad * 4 + r][col] = gelu(acc[g][r] + bc);
  }
  __syncthreads();

  // --- Head: 128 threads, (row, o) each split 4-way over K=128, shfl-reduce.
  if (tid < 128) {
    const int row = tid >> 3, o = (tid >> 2) & 1, q4 = tid & 3;
    float part = 0.f;
#pragma unroll 8
    for (int c = q4; c < 128; c += 4) part += S2[row][c] * w3[c * 2 + o];
    part += __shfl_xor(part, 1);
    part += __shfl_xor(part, 2);
    if (q4 == 0) {
      const int pair = m0 + row;
      const float a = part + b3[o];
      const float qmf = (float)qmask[pair];
      out[pair * 2 + o] = ((1.f / (1.f + expf(-a))) * 8.f + 1.f) * qmf;
    }
  }
}

// ---------------------------------------------------------------------------
extern "C" void kernel_launch(void* const* d_in, const int* in_sizes, int n_in,
                              void* d_out, int out_size, void* d_ws,
                              size_t ws_size, hipStream_t stream) {
  const float* hs = (const float*)d_in[0];   // f32 64x512x1024
  const int* spans = (const int*)d_in[1];
  const int* qmask = (const int*)d_in[2];
  const float* W1 = (const float*)d_in[3];   // f32 3072x256
  const float* b1 = (const float*)d_in[4];
  const float* W2 = (const float*)d_in[5];   // f32 256x128
  const float* b2 = (const float*)d_in[6];
  const float* W3 = (const float*)d_in[7];   // f32 128x2
  const float* b3 = (const float*)d_in[8];
  float* out = (float*)d_out;

  const size_t HPAIR_B = 25165824;  // 4096*3072 bf16
  const size_t P_B = 8388608;       // 2 x 4096*256 f32

  char* ws = (char*)d_ws;
  size_t off = 0;
  unsigned short* hpair = (unsigned short*)(ws + off); off += HPAIR_B;
  float* P = (float*)(ws + off);                       off += P_B;
  unsigned short* W1T = (unsigned short*)(ws + off);

  transpose_w1<<<768, dim3(32, 8), 0, stream>>>(W1, W1T);
  pool_mfma_kernel<<<1024, 256, 0, stream>>>(hs, spans, qmask, hpair);
  gemm_bt_partial<<<dim3(64, 4, 2), 256, 0, stream>>>(hpair, W1T, P, NPAIR,
                                                      256, 3072, 1536);
  tail_kernel<<<256, 256, 0, stream>>>(P, b1, W2, b2, W3, b3, qmask, out);
}

// Round 2
// 237.181 us; speedup vs baseline: 1.1284x; 1.1284x over previous
//
#include <hip/hip_runtime.h>
#include <math.h>

// SpanPairVAHead on MI355X (gfx950).
// Dtype map (established rounds 0-3): ALL float tensors f32, spans int
// (32/64 sniffed on device), OUTPUT f32. Internal activations bf16 for MFMA.
//
// R9: (1) fix R8's tail regression — restore one-time W2T transpose (rides in
// the W1 transpose launch); tail loads B-frags DIRECTLY from W2T global
// (L2-resident 64 KB, no Bl LDS, no redundant f32->bf16 per block). Only the
// x1 tile is LDS-staged; single barrier. (2) GEMM1 upgraded 64^2 -> 128^2
// m97-structure: double-buffered LDS, global_load_lds w=16, stage-before-
// compute, ONE barrier per K-step (T3-minimum 2-phase), split-K z=4.
// 4 launches.
//
// B=64, L=512, H=1024, Q=64, VA_H=256. Pairs = B*Q = 4096.

typedef __attribute__((ext_vector_type(4))) float f32x4;
typedef __attribute__((ext_vector_type(8))) short bf16x8;

#define NPAIR 4096
#define LSEQ 512
#define HDIM 1024

#if defined(__has_builtin)
#if __has_builtin(__builtin_amdgcn_global_load_lds)
#define HAVE_GLDS 1
#endif
#endif
#ifndef HAVE_GLDS
#define HAVE_GLDS 0
#endif

// Pack two f32 -> bf16 pair, round-to-nearest (half-up; differs from RNE only
// on exact ties, p~2^-16). v_perm_b32 grabs the two high halves.
__device__ __forceinline__ unsigned int pack2(float lo, float hi) {
  const unsigned int a = __float_as_uint(lo) + 0x8000u;
  const unsigned int b = __float_as_uint(hi) + 0x8000u;
  return __builtin_amdgcn_perm(b, a, 0x07060302u);
}
__device__ __forceinline__ unsigned short f2bf(float f) {
  return (unsigned short)((__float_as_uint(f) + 0x8000u) >> 16);
}
__device__ __forceinline__ float gelu(float x) {
  return 0.5f * x * (1.f + erff(x * 0.70710678118654752f));
}

// ---------------------------------------------------------------------------
// Fused span pooling via MFMA (unchanged from R7). One block per (batch,
// 64-col H-slice): 1024 blocks = 4/CU. Rows 0..63 = asp masks, 64..127 = opi.
// A-frags from span compares in registers; B staged f32->bf16 transposed
// ([n][k]) double-buffered, 1 barrier/iter. Epilogue S[128][68] unions Bl.
// ---------------------------------------------------------------------------
__global__ __launch_bounds__(256, 4) void pool_mfma_kernel(
    const float* __restrict__ hs, const int* __restrict__ spans,
    const int* __restrict__ qmask, unsigned short* __restrict__ hpair) {
  __shared__ __align__(16) unsigned char smem[34816];  // max(2*64*40*2, 128*68*4)
  __shared__ float scl[128];
  typedef unsigned short BlT[64][40];
  BlT* Bl = (BlT*)smem;                  // Bl[2][64][40]
  float(*S)[68] = (float(*)[68])smem;    // S[128][68] (epilogue only)

  const int b = blockIdx.x >> 4;
  const int n0 = (blockIdx.x & 15) * 64;
  const int tid = threadIdx.x;
  const int lane = tid & 63;
  const int lm = lane & 15, quad = lane >> 4;
  const int wm = (tid >> 6) * 32;  // wave's mask-row base

  const bool is64 =
      (spans[1] == 0) && (spans[3] == 0) && (spans[5] == 0) && (spans[7] == 0);

  auto span_of = [&](int r, int& s, int& e) {
    const int q = r & 63, t = r >> 6;
    const int idx = (b * 64 + q) * 4 + t * 2;
    s = is64 ? spans[idx * 2] : spans[idx];
    e = is64 ? spans[idx * 2 + 2] : spans[idx + 1];
    if (s < 2) { s = 1; e = 1; }  // invalid -> [SEP]
  };
  int s0, e0, s1, e1;
  span_of(wm + lm, s0, e0);
  span_of(wm + 16 + lm, s1, e1);

  if (tid < 128) {
    int s, e;
    span_of(tid, s, e);
    const int c = (e >= s) ? (e - s + 1) : 0;
    const float sc = 1.f / (float)(c < 1 ? 1 : c);
    scl[tid] = (qmask[b * 64 + (tid & 63)] != 0) ? sc : 0.f;
  }

  f32x4 acc[2][4];
#pragma unroll
  for (int f = 0; f < 2; ++f)
#pragma unroll
    for (int g = 0; g < 4; ++g) acc[f][g] = f32x4{0.f, 0.f, 0.f, 0.f};

  const float* hsb = hs + (size_t)b * (LSEQ * HDIM);
  const int nl = tid & 63;        // staged column (wave-coalesced)
  const int kw = (tid >> 6) * 8;  // wave's k-offset within 32-chunk

  auto load8 = [&](int kbase, unsigned int (&tmp)[4]) {
    const float* src = hsb + (size_t)(kbase + kw) * HDIM + n0 + nl;
#pragma unroll
    for (int i = 0; i < 4; ++i) {
      const float f0 = src[(size_t)(2 * i) * HDIM];
      const float f1 = src[(size_t)(2 * i + 1) * HDIM];
      tmp[i] = pack2(f0, f1);
    }
  };

  unsigned int tmp[4];
  load8(0, tmp);
  *(uint4*)&Bl[0][nl][kw] = make_uint4(tmp[0], tmp[1], tmp[2], tmp[3]);

  for (int it = 0; it < 16; ++it) {
    const int k0 = it * 32;
    __syncthreads();  // buf[it&1] staged; prior reads of buf[(it+1)&1] done
    if (it < 15) load8(k0 + 32, tmp);

    bf16x8 a0, a1;
#pragma unroll
    for (int j = 0; j < 8; ++j) {
      const int k = k0 + quad * 8 + j;
      a0[j] = (short)((k >= s0 && k <= e0) ? 0x3F80 : 0);
      a1[j] = (short)((k >= s1 && k <= e1) ? 0x3F80 : 0);
    }
    const BlT& Bc = Bl[it & 1];
#pragma unroll
    for (int g = 0; g < 4; ++g) {
      bf16x8 bg = *(const bf16x8*)&Bc[g * 16 + lm][quad * 8];
      acc[0][g] = __builtin_amdgcn_mfma_f32_16x16x32_bf16(a0, bg, acc[0][g], 0, 0, 0);
      acc[1][g] = __builtin_amdgcn_mfma_f32_16x16x32_bf16(a1, bg, acc[1][g], 0, 0, 0);
    }
    if (it < 15) {
      *(uint4*)&Bl[(it + 1) & 1][nl][kw] = make_uint4(tmp[0], tmp[1], tmp[2], tmp[3]);
    }
  }

  __syncthreads();  // all MFMA LDS reads done before S overwrites Bl
  // C/D layout (m89): col = lane&15, row = quad*4 + reg.
#pragma unroll
  for (int f = 0; f < 2; ++f)
#pragma unroll
    for (int g = 0; g < 4; ++g)
#pragma unroll
      for (int r = 0; r < 4; ++r)
        S[wm + f * 16 + quad * 4 + r][g * 16 + lm] = acc[f][g][r];
  __syncthreads();

  // Store h_pair: thread q = tid>>2, 16-col group cg = (tid&3)*16.
  const int q = tid >> 2;
  const int cg = (tid & 3) * 16;
  const float sA = scl[q], sO = scl[64 + q];
  unsigned short* dst = hpair + (size_t)(b * 64 + q) * 3072 + n0 + cg;
#pragma unroll
  for (int h = 0; h < 2; ++h) {
    float a[8], o[8];
#pragma unroll
    for (int i = 0; i < 8; ++i) {
      a[i] = S[q][cg + h * 8 + i] * sA;
      o[i] = S[64 + q][cg + h * 8 + i] * sO;
    }
    uint4 wa, wo, wp;
    wa.x = pack2(a[0], a[1]); wa.y = pack2(a[2], a[3]);
    wa.z = pack2(a[4], a[5]); wa.w = pack2(a[6], a[7]);
    wo.x = pack2(o[0], o[1]); wo.y = pack2(o[2], o[3]);
    wo.z = pack2(o[4], o[5]); wo.w = pack2(o[6], o[7]);
    wp.x = pack2(a[0] * o[0], a[1] * o[1]); wp.y = pack2(a[2] * o[2], a[3] * o[3]);
    wp.z = pack2(a[4] * o[4], a[5] * o[5]); wp.w = pack2(a[6] * o[6], a[7] * o[7]);
    *(uint4*)(dst + h * 8) = wa;
    *(uint4*)(dst + 1024 + h * 8) = wo;
    *(uint4*)(dst + 2048 + h * 8) = wp;
  }
}

// ---------------------------------------------------------------------------
// Both weight transposes in one launch (restored from R7 — one-time cost,
// rides alongside W1). Blocks 0..767: W1 (3072x256); 768..799: W2 (256x128).
// f32 in -> bf16 out, transposed.
// ---------------------------------------------------------------------------
__global__ void transpose_two(const float* __restrict__ W1,
                              unsigned short* __restrict__ W1T,
                              const float* __restrict__ W2,
                              unsigned short* __restrict__ W2T) {
  __shared__ float t[32][33];
  const float* in;
  unsigned short* out;
  int R, C, c0, r0;
  int blk = blockIdx.x;
  if (blk < 768) {
    in = W1; out = W1T; R = 3072; C = 256;
    c0 = (blk & 7) * 32; r0 = (blk >> 3) * 32;
  } else {
    blk -= 768;
    in = W2; out = W2T; R = 256; C = 128;
    c0 = (blk & 3) * 32; r0 = (blk >> 2) * 32;
  }
  const int x = threadIdx.x, y = threadIdx.y;  // (32, 8)
#pragma unroll
  for (int i = 0; i < 32; i += 8)
    t[y + i][x] = in[(size_t)(r0 + y + i) * C + c0 + x];
  __syncthreads();
#pragma unroll
  for (int i = 0; i < 32; i += 8)
    out[(size_t)(c0 + y + i) * R + r0 + x] = f2bf(t[x][y + i]);
}

// ---------------------------------------------------------------------------
// Split-K GEMM1 partial, 128x128 tile (m97 structure): P[z] = A slice @ Bt^T.
// BK=32, 4 waves (2x2), 4x4 16x16 frags/wave, global_load_lds w=16 into
// double-buffered unpadded [128][32] LDS (lane i -> wavebase + 16*i, m104
// constraint). Stage(t+1) issued BEFORE compute(t); ONE barrier per K-step
// (T3-minimum 2-phase) — load latency hides under ds_read+MFMA.
// Grid (M/128, N/128, KSPLIT) = (32, 2, 4), KH = 768 -> 24 K-steps.
// ---------------------------------------------------------------------------
__global__ __launch_bounds__(256) void gemm_bt_128(
    const unsigned short* __restrict__ A, const unsigned short* __restrict__ Bt,
    float* __restrict__ P, int M, int N, int K, int KH) {
  __shared__ __align__(16) unsigned short Al[2][128][32];
  __shared__ __align__(16) unsigned short Bl[2][128][32];
  const int bm = blockIdx.x * 128, bn = blockIdx.y * 128;
  const int kz = blockIdx.z * KH;
  const int tid = threadIdx.x;
  const int wave = tid >> 6, lane = tid & 63;
  const int wm = (wave & 1) * 64, wn = (wave >> 1) * 64;
  const int lm = lane & 15, lk = (lane >> 4) * 8;

  // Staging: wave stages rows [wave*32, wave*32+32) of each matrix = two
  // global_load_lds calls (16 rows x 32 cols = 1 KB each).
  const int srow = wave * 32 + (lane >> 2);
  const int scol = (lane & 3) * 8;
  const unsigned short* ga = A + (size_t)(bm + srow) * K + kz + scol;
  const unsigned short* gb = Bt + (size_t)(bn + srow) * K + kz + scol;
  unsigned short* laA[2] = {&Al[0][wave * 32][0], &Al[1][wave * 32][0]};
  unsigned short* laB[2] = {&Bl[0][wave * 32][0], &Bl[1][wave * 32][0]};

  f32x4 acc[4][4];
#pragma unroll
  for (int i = 0; i < 4; ++i)
#pragma unroll
    for (int j = 0; j < 4; ++j) acc[i][j] = f32x4{0.f, 0.f, 0.f, 0.f};

  auto stage = [&](int u, int k0) {
#if HAVE_GLDS
    __builtin_amdgcn_global_load_lds(ga + k0, laA[u], 16, 0, 0);
    __builtin_amdgcn_global_load_lds(ga + (size_t)16 * K + k0, laA[u] + 16 * 32, 16, 0, 0);
    __builtin_amdgcn_global_load_lds(gb + k0, laB[u], 16, 0, 0);
    __builtin_amdgcn_global_load_lds(gb + (size_t)16 * K + k0, laB[u] + 16 * 32, 16, 0, 0);
#else
    *(uint4*)(laA[u] + lane * 8) = *(const uint4*)(ga + k0);
    *(uint4*)(laA[u] + 16 * 32 + lane * 8) = *(const uint4*)(ga + (size_t)16 * K + k0);
    *(uint4*)(laB[u] + lane * 8) = *(const uint4*)(gb + k0);
    *(uint4*)(laB[u] + 16 * 32 + lane * 8) = *(const uint4*)(gb + (size_t)16 * K + k0);
#endif
  };

  const int NT = KH / 32;  // 24
  stage(0, 0);
  for (int t = 0; t < NT; ++t) {
    __syncthreads();  // buf[t&1] staged (vmcnt drained); prior buf reads done
    if (t + 1 < NT) stage((t + 1) & 1, (t + 1) * 32);
    const int u = t & 1;
    bf16x8 af[4], bf[4];
#pragma unroll
    for (int i = 0; i < 4; ++i) {
      af[i] = *(const bf16x8*)&Al[u][wm + i * 16 + lm][lk];
      bf[i] = *(const bf16x8*)&Bl[u][wn + i * 16 + lm][lk];
    }
#pragma unroll
    for (int i = 0; i < 4; ++i)
#pragma unroll
      for (int j = 0; j < 4; ++j)
        acc[i][j] = __builtin_amdgcn_mfma_f32_16x16x32_bf16(af[i], bf[j], acc[i][j], 0, 0, 0);
  }

  float* Pz = P + (size_t)blockIdx.z * M * N;
  const int rq = (lane >> 4) << 2;
#pragma unroll
  for (int i = 0; i < 4; ++i)
#pragma unroll
    for (int j = 0; j < 4; ++j) {
      const int r0 = bm + wm + i * 16 + rq;
      const int c0 = bn + wn + j * 16 + lm;
#pragma unroll
      for (int r = 0; r < 4; ++r)
        Pz[(size_t)(r0 + r) * N + c0] = acc[i][j][r];
    }
}

// ---------------------------------------------------------------------------
// Fused tail: split-K reduce (4 partials) + b1 + gelu -> x1 tile (LDS),
// GEMM2 (16x128, K=256) with B-frags loaded DIRECTLY from W2T global
// (64 KB, L2-resident, shared by all blocks — no per-block conversion),
// gelu+b2 -> S2, head dot W3, sigmoid*8+1, *qmask. 256 blocks x 16 pairs
// = 1 block/CU. ONE barrier in the whole kernel.
// ---------------------------------------------------------------------------
__global__ __launch_bounds__(256) void tail_kernel(
    const float* __restrict__ P, const float* __restrict__ b1,
    const unsigned short* __restrict__ W2T, const float* __restrict__ b2,
    const float* __restrict__ W3, const float* __restrict__ b3,
    const int* __restrict__ qmask, float* __restrict__ out) {
  __shared__ __align__(16) unsigned short Al[16 * 264];  // x1 tile, 528B rows
  __shared__ float S2[16][132];                          // x2 tile f32
  __shared__ float w3[256];

  const int m0 = blockIdx.x * 16;
  const int tid = threadIdx.x;
  const int wave = tid >> 6, lane = tid & 63;
  const int lm = lane & 15, quad = lane >> 4;
  const int wn = wave * 32;  // wave's 32-col slice of N=128

  w3[tid] = W3[tid];  // 128x2 f32

  // --- Stage x1 tile: x1[r][k] = gelu(sum_z P[z] + b1). 16 elems/thread,
  // coalesced float4 reads of P.
  {
    const int row = tid >> 4;   // 0..15
    const int slot = tid & 15;  // 8-elem slot
#pragma unroll
    for (int ss = 0; ss < 2; ++ss) {
      const int s = slot + ss * 16;  // 0..31
      const float* pb = P + (size_t)(m0 + row) * 256 + s * 8;
      float v[8];
      {
        float4 ba = *(const float4*)(b1 + s * 8);
        float4 bb = *(const float4*)(b1 + s * 8 + 4);
        v[0] = ba.x; v[1] = ba.y; v[2] = ba.z; v[3] = ba.w;
        v[4] = bb.x; v[5] = bb.y; v[6] = bb.z; v[7] = bb.w;
      }
#pragma unroll
      for (int z = 0; z < 4; ++z) {
        const float* pz = pb + (size_t)z * ((size_t)NPAIR * 256);
        float4 a0 = *(const float4*)pz;
        float4 a1 = *(const float4*)(pz + 4);
        v[0] += a0.x; v[1] += a0.y; v[2] += a0.z; v[3] += a0.w;
        v[4] += a1.x; v[5] += a1.y; v[6] += a1.z; v[7] += a1.w;
      }
      uint4 w;
      w.x = pack2(gelu(v[0]), gelu(v[1]));
      w.y = pack2(gelu(v[2]), gelu(v[3]));
      w.z = pack2(gelu(v[4]), gelu(v[5]));
      w.w = pack2(gelu(v[6]), gelu(v[7]));
      *(uint4*)((char*)Al + (size_t)row * 528 + s * 16) = w;
    }
  }
  __syncthreads();  // Al ready; LDS read-only from here

  // --- GEMM2: M=16 (1 frag), N=128 (2 frags/wave), K=256 (8 steps).
  // B-frags straight from W2T[n][k] global (row n = wn+g*16+lm, 16B-aligned).
  f32x4 acc[2];
  acc[0] = f32x4{0.f, 0.f, 0.f, 0.f};
  acc[1] = f32x4{0.f, 0.f, 0.f, 0.f};
#pragma unroll
  for (int ks = 0; ks < 8; ++ks) {
    bf16x8 a = *(const bf16x8*)((char*)Al + (size_t)lm * 528 + ks * 64 + quad * 16);
#pragma unroll
    for (int g = 0; g < 2; ++g) {
      const int n = wn + g * 16 + lm;
      bf16x8 b = *(const bf16x8*)(W2T + (size_t)n * 256 + ks * 32 + quad * 8);
      acc[g] = __builtin_amdgcn_mfma_f32_16x16x32_bf16(a, b, acc[g], 0, 0, 0);
    }
  }

  // --- x2 = gelu(acc + b2). C/D: col = lane&15, row = quad*4 + reg.
#pragma unroll
  for (int g = 0; g < 2; ++g) {
    const int col = wn + g * 16 + lm;
    const float bc = b2[col];
#pragma unroll
    for (int r = 0; r < 4; ++r) S2[quad * 4 + r][col] = gelu(acc[g][r] + bc);
  }
  __syncthreads();

  // --- Head: 128 threads, (row, o) each split 4-way over K=128, shfl-reduce.
  if (tid < 128) {
    const int row = tid >> 3, o = (tid >> 2) & 1, q4 = tid & 3;
    float part = 0.f;
#pragma unroll 8
    for (int c = q4; c < 128; c += 4) part += S2[row][c] * w3[c * 2 + o];
    part += __shfl_xor(part, 1);
    part += __shfl_xor(part, 2);
    if (q4 == 0) {
      const int pair = m0 + row;
      const float a = part + b3[o];
      const float qmf = (float)qmask[pair];
      out[pair * 2 + o] = ((1.f / (1.f + expf(-a))) * 8.f + 1.f) * qmf;
    }
  }
}

// ---------------------------------------------------------------------------
extern "C" void kernel_launch(void* const* d_in, const int* in_sizes, int n_in,
                              void* d_out, int out_size, void* d_ws,
                              size_t ws_size, hipStream_t stream) {
  const float* hs = (const float*)d_in[0];   // f32 64x512x1024
  const int* spans = (const int*)d_in[1];
  const int* qmask = (const int*)d_in[2];
  const float* W1 = (const float*)d_in[3];   // f32 3072x256
  const float* b1 = (const float*)d_in[4];
  const float* W2 = (const float*)d_in[5];   // f32 256x128
  const float* b2 = (const float*)d_in[6];
  const float* W3 = (const float*)d_in[7];   // f32 128x2
  const float* b3 = (const float*)d_in[8];
  float* out = (float*)d_out;

  const size_t HPAIR_B = 25165824;  // 4096*3072 bf16
  const size_t P_B = 16777216;      // 4 x 4096*256 f32
  const size_t W1T_B = 1572864;     // 256*3072 bf16

  char* ws = (char*)d_ws;
  size_t off = 0;
  unsigned short* hpair = (unsigned short*)(ws + off); off += HPAIR_B;
  float* P = (float*)(ws + off);                       off += P_B;
  unsigned short* W1T = (unsigned short*)(ws + off);   off += W1T_B;
  unsigned short* W2T = (unsigned short*)(ws + off);

  transpose_two<<<800, dim3(32, 8), 0, stream>>>(W1, W1T, W2, W2T);
  pool_mfma_kernel<<<1024, 256, 0, stream>>>(hs, spans, qmask, hpair);
  gemm_bt_128<<<dim3(32, 2, 4), 256, 0, stream>>>(hpair, W1T, P, NPAIR,
                                                  256, 3072, 768);
  tail_kernel<<<256, 256, 0, stream>>>(P, b1, W2T, b2, W3, b3, qmask, out);
}